// Round 10
// baseline (314.540 us; speedup 1.0000x reference)
//
#include <hip/hip_runtime.h>
#include <hip/hip_bf16.h>
#include <stdint.h>

typedef __bf16 bf16_t;
typedef __bf16 bf16x8 __attribute__((ext_vector_type(8)));
typedef short short8 __attribute__((ext_vector_type(8)));
typedef float f32x4 __attribute__((ext_vector_type(4)));

#define RS512  0.044194173824159216f   // 1/sqrt(512)
#define RS4608 0.014731391274719739f   // 1/sqrt(512*9)

// ---------------- K1: style vector  s[b][c] = (w[b,:] . lw[c,:])/sqrt(512) + lb[c]
__global__ void k_style(const float* __restrict__ w, const float* __restrict__ lw,
                        const float* __restrict__ lb, float* __restrict__ s) {
  int b = blockIdx.y;
  int c = blockIdx.x * 256 + threadIdx.x;
  const float4* wr = (const float4*)(w + b * 512);
  const float4* lr = (const float4*)(lw + (size_t)c * 512);
  float acc = 0.f;
#pragma unroll 4
  for (int d = 0; d < 128; ++d) {
    float4 a = wr[d], q = lr[d];
    acc += a.x * q.x + a.y * q.y + a.z * q.z + a.w * q.w;
  }
  s[b * 512 + c] = acc * RS512 + lb[c];
}

// ---------------- K2: wsq + bf16 W fragments; also zero-fills the 4KB zero-region
__global__ void k_wprep(const float* __restrict__ cw, float* __restrict__ wsq,
                        bf16_t* __restrict__ bwf, f32x4* __restrict__ zb) {
  if (blockIdx.x == 0) zb[threadIdx.x] = (f32x4)0.f;  // 256*16B = 4KB zeros
  int idx = blockIdx.x * 256 + threadIdx.x;  // o*512 + i
  int o = idx >> 9, i = idx & 511;
  float v[9];
  float ss = 0.f;
#pragma unroll
  for (int t = 0; t < 9; ++t) {
    float x = cw[(size_t)idx * 9 + t] * RS4608;
    v[t] = x;
    ss += x * x;
  }
  wsq[idx] = ss;
  int lane = (o & 15) | (((i >> 3) & 3) << 4);
  int base_blk = (i >> 5) * 32 + (o >> 4);  // c32*32 + fo
#pragma unroll
  for (int t = 0; t < 9; ++t) {
    size_t e = ((size_t)(t * 512 + base_blk) << 9) + lane * 8 + (i & 7);
    bwf[e] = (bf16_t)v[t];
  }
}

// ---------------- K3: sigma_inv[b][o] = rsqrt( sum_i s[b,i]^2 * wsq[o,i] + eps )
__global__ void k_sigma(const float* __restrict__ s, const float* __restrict__ wsq,
                        float* __restrict__ sinv) {
  __shared__ float s2[512];
  int b = blockIdx.y;
  int o = blockIdx.x * 256 + threadIdx.x;
  for (int i = threadIdx.x; i < 512; i += 256) {
    float v = s[b * 512 + i];
    s2[i] = v * v;
  }
  __syncthreads();
  const float4* qr = (const float4*)(wsq + (size_t)o * 512);
  float acc = 0.f;
#pragma unroll 4
  for (int d = 0; d < 128; ++d) {
    float4 q = qr[d];
    acc += q.x * s2[4 * d] + q.y * s2[4 * d + 1] + q.z * s2[4 * d + 2] + q.w * s2[4 * d + 3];
  }
  sinv[b * 512 + o] = rsqrtf(acc + 1e-8f);
}

// ---------------- K4: xt[b][h][w][ch] = bf16( x[b][ch][h][w] * s[b][ch] ), slot-permuted
__global__ void k_xt(const float* __restrict__ x, const float* __restrict__ s,
                     bf16_t* __restrict__ xt) {
  int ic = blockIdx.x, h = blockIdx.y, b = blockIdx.z;
  __shared__ __align__(16) bf16_t tile[8192];
  int t = threadIdx.x;
  int wcol = t & 63;
  int g = t >> 6;
#pragma unroll
  for (int blk = 0; blk < 4; ++blk) {
    int grp = blk * 4 + g;
    bf16x8 vec;
#pragma unroll
    for (int k = 0; k < 8; ++k) {
      int i = ic * 128 + grp * 8 + k;
      float v = x[(((size_t)b * 512 + i) * 64 + h) * 64 + wcol] * s[b * 512 + i];
      vec[k] = (bf16_t)v;
    }
    int chunk = grp ^ (wcol & 15);
    *(bf16x8*)((char*)tile + wcol * 256 + chunk * 16) = vec;
  }
  __syncthreads();
#pragma unroll
  for (int j = 0; j < 4; ++j) {
    int flat = j * 256 + t;
    int wo = flat >> 4, ig8 = flat & 15;
    int chunk = ig8 ^ (wo & 15);
    bf16x8 v = *(bf16x8*)((char*)tile + wo * 256 + chunk * 16);
    int c32 = (ig8 >> 2);
    int slot = (ig8 & 3) ^ ((wo >> 1) & 3);
    *(bf16x8*)(xt + (((size_t)b * 64 + h) * 64 + wo) * 512 + ic * 128 + c32 * 32 + slot * 8) = v;
  }
}

// ---------------- K5: implicit-GEMM conv; kx-major tap order with ky-rolling B reuse
#define AS1 __attribute__((address_space(1)))
#define AS3 __attribute__((address_space(3)))

__device__ __forceinline__ void gl16(const void* g, void* l) {
  __builtin_amdgcn_global_load_lds((const AS1 void*)g, (AS3 void*)l, 16, 0, 0);
}

#define VMCNT(n) asm volatile("s_waitcnt vmcnt(" #n ")" ::: "memory")
#define BAR __builtin_amdgcn_s_barrier()

// consumption index jc (0..8): kx = jc/3, ky = jc%3, tap = (jc%3)*3 + jc/3
#define TMAP(jc) ((((jc) % 3) * 3) + ((jc) / 3))

// LDS map: W[3 slabs][8192B] @0..24575 ; X[2 bufs][6 rows][4096B] @24576..73727
__global__ __launch_bounds__(256, 2) void k_conv(
    const bf16_t* __restrict__ xt, const bf16_t* __restrict__ bwf,
    const float* __restrict__ sinv, const float* __restrict__ noise,
    const float* __restrict__ snz, const float* __restrict__ bias,
    const char* __restrict__ zb, float* __restrict__ out) {
  __shared__ __align__(16) char lds[73728];

  const int t = threadIdx.x;
  const int rq = blockIdx.x;        // output rows h0..h0+3
  const int OY = blockIdx.y;        // o0 = OY*128
  const int b = blockIdx.z;
  const int h0 = rq * 4;
  const int lane = t & 63;
  const int wv = t >> 6;
  const int wm = wv >> 1;           // o-offset wm*64
  const int wn = wv & 1;            // rows h0+wn*2 .. +1

  // persistent byte-based staging pointers
  const char* xg = (const char*)xt + (size_t)b * 4194304 + (t >> 2) * 1024 + (t & 3) * 16;
  const char* wgp = (const char*)bwf + OY * 8192 + wv * 2048 + lane * 16;
  const char* zgv = zb + t * 16;

  f32x4 acc[4][8] = {};
  bf16x8 RA[4], RB[4];              // rolling B-fragment rows (live across phases)

  // LDS read offsets
  const uint32_t woff = (uint32_t)((wm << 12) + (lane << 4));  // within an 8KB slab
  uint32_t pX[4][3];
#pragma unroll
  for (int j = 0; j < 4; ++j)
#pragma unroll
    for (int dk = 0; dk < 3; ++dk) {
      int icol = j * 16 + (lane & 15) + dk - 1;
      int ic2 = icol < 0 ? 0 : (icol > 63 ? 63 : icol);
      int slot = (lane >> 4) ^ ((ic2 >> 1) & 3);
      pX[j][dk] = (uint32_t)(24576 + wn * 8192 + ic2 * 64 + slot * 16);
    }
  const bool c0 = (lane & 15) == 0;
  const bool c15 = (lane & 15) == 15;

  auto stW = [&](uint32_t srcByteOff, int slab) {  // one 8KB tap slab: 2 gl16/thread
    const char* s0 = wgp + srcByteOff;
    gl16(s0, lds + slab * 8192 + (wv << 11));
    gl16(s0 + 1024, lds + slab * 8192 + (wv << 11) + 1024);
  };
  auto stX = [&](int r, uint32_t cxoff, int xb) {  // one 4KB row: 1 gl16/thread
    int gr = h0 - 1 + r;
    char* d = lds + 24576 + xb * 24576 + r * 4096 + (wv << 10);
    if ((unsigned)gr < 64u) gl16(xg + (size_t)gr * 65536 + cxoff, d);
    else gl16(zgv, d);  // real zeros (uniform vmem count)
  };

// load one B row (4 col-fragments) with edge masks; RREL/KX compile-time
#define LROW(DST, RREL, KX, XB)                                                \
  {                                                                            \
    _Pragma("unroll") for (int col = 0; col < 4; ++col) {                      \
      short8 xv = *(const short8*)(lds + pX[col][(KX)] +                       \
                                   (uint32_t)((XB) * 24576 + (RREL) * 4096));  \
      if ((KX) == 0 && col == 0) xv = c0 ? (short8)0 : xv;                     \
      if ((KX) == 2 && col == 3) xv = c15 ? (short8)0 : xv;                    \
      DST[col] = __builtin_bit_cast(bf16x8, xv);                               \
    }                                                                          \
  }

#define MFMABLK(LO, HI)                                                        \
  {                                                                            \
    __builtin_amdgcn_s_setprio(1);                                             \
    _Pragma("unroll") for (int mi = 0; mi < 4; ++mi) {                         \
      _Pragma("unroll") for (int col = 0; col < 4; ++col) {                    \
        acc[mi][col] = __builtin_amdgcn_mfma_f32_16x16x32_bf16(                \
            af[mi], LO[col], acc[mi][col], 0, 0, 0);                           \
        acc[mi][col + 4] = __builtin_amdgcn_mfma_f32_16x16x32_bf16(            \
            af[mi], HI[col], acc[mi][col + 4], 0, 0, 0);                       \
      }                                                                        \
    }                                                                          \
    __builtin_amdgcn_s_setprio(0);                                             \
  }

// COMP: A-frags from slab jc%3; B rows rolled across ky (kx fixed per 3 phases)
#define COMP(JC, XB)                                                           \
  {                                                                            \
    bf16x8 af[4];                                                              \
    _Pragma("unroll") for (int mi = 0; mi < 4; ++mi)                           \
        af[mi] = *(const bf16x8*)(lds + (uint32_t)(((JC) % 3) * 8192) + woff + \
                                  (uint32_t)(mi * 1024));                      \
    if ((JC) % 3 == 0) {                                                       \
      LROW(RA, 0, (JC) / 3, XB); LROW(RB, 1, (JC) / 3, XB);                    \
      MFMABLK(RA, RB);                                                         \
    } else if ((JC) % 3 == 1) {                                                \
      LROW(RA, 2, (JC) / 3, XB);                                               \
      MFMABLK(RB, RA);                                                         \
    } else {                                                                   \
      LROW(RB, 3, (JC) / 3, XB);                                               \
      MFMABLK(RA, RB);                                                         \
    }                                                                          \
  }

// phase: X-stage (rows of chunk c+1, phases 0-5), W-stage (consumption jc+2),
// counted vmcnt (ledger {5,6,6,6,6,6,5,4,4} / last {4x7,2,0}), barrier, compute.
#define PHASE(CWB, CXB, JC, LAST, XB)                                          \
  {                                                                            \
    if (!(LAST) && (JC) < 6) stX((JC), (CXB), (XB) ^ 1);                       \
    if (!(LAST) || (JC) <= 6) {                                                \
      if ((JC) + 2 <= 8)                                                       \
        stW((CWB) + (uint32_t)(TMAP((JC) + 2)) * 524288u, ((JC) + 2) % 3);     \
      else                                                                     \
        stW((CWB) + 32768u + (uint32_t)(TMAP((JC) - 7)) * 524288u,             \
            ((JC) + 2) % 3);                                                   \
    }                                                                          \
    if (LAST) {                                                                \
      if ((JC) <= 6) { VMCNT(4); }                                             \
      else if ((JC) == 7) { VMCNT(2); }                                        \
      else { VMCNT(0); }                                                       \
    } else {                                                                   \
      if ((JC) == 0 || (JC) == 6) { VMCNT(5); }                                \
      else if ((JC) <= 5) { VMCNT(6); }                                        \
      else { VMCNT(4); }                                                       \
    }                                                                          \
    __builtin_amdgcn_s_barrier();                                              \
    COMP((JC), (XB));                                                          \
  }

  // prologue: X[0] (zeros for halo rows) + W consumptions 0,1 (taps 0,3) -> slabs 0,1
#pragma unroll
  for (int r = 0; r < 6; ++r) stX(r, 0u, 0);
  stW(0u * 524288u, 0);
  stW(3u * 524288u, 1);
  VMCNT(0); BAR;

  uint32_t cwb = 0, cxb = 64;
#pragma unroll 1
  for (int ci = 0; ci < 7; ++ci) {
#pragma unroll
    for (int jc = 0; jc < 9; ++jc) PHASE(cwb, cxb, jc, 0, 0);
    cwb += 32768u; cxb += 64u;
#pragma unroll
    for (int jc = 0; jc < 9; ++jc) PHASE(cwb, cxb, jc, 0, 1);
    cwb += 32768u; cxb += 64u;
  }
#pragma unroll
  for (int jc = 0; jc < 9; ++jc) PHASE(cwb, cxb, jc, 0, 0);  // chunk 14
  cwb += 32768u;
#pragma unroll
  for (int jc = 0; jc < 9; ++jc) PHASE(cwb, cxb, jc, 1, 1);  // chunk 15 (LAST)

  // epilogue: demod scale + noise + bias + leaky relu
  const float* sb = sinv + b * 512;
  const int og = OY * 128 + wm * 64 + ((lane >> 4) << 2);
  const int colb = lane & 15;
  float nzv[8];
#pragma unroll
  for (int ni = 0; ni < 8; ++ni) {
    int prow = h0 + wn * 2 + (ni >> 2);
    nzv[ni] = noise[(size_t)b * 4096 + prow * 64 + (ni & 3) * 16 + colb];
  }
#pragma unroll
  for (int mi = 0; mi < 4; ++mi) {
#pragma unroll
    for (int r = 0; r < 4; ++r) {
      int o = og + mi * 16 + r;
      float sv = sb[o];
      float nw = snz[o];
      float bv = bias[o];
      float* obase = out + ((size_t)b * 512 + o) * 4096;
#pragma unroll
      for (int ni = 0; ni < 8; ++ni) {
        int prow = h0 + wn * 2 + (ni >> 2);
        int col = (ni & 3) * 16 + colb;
        float v = acc[mi][ni][r] * sv + nw * nzv[ni] + bv;
        obase[prow * 64 + col] = v > 0.f ? v : 0.2f * v;
      }
    }
  }
}

extern "C" void kernel_launch(void* const* d_in, const int* in_sizes, int n_in,
                              void* d_out, int out_size, void* d_ws, size_t ws_size,
                              hipStream_t stream) {
  const float* x     = (const float*)d_in[0];
  const float* w     = (const float*)d_in[1];
  const float* noise = (const float*)d_in[2];
  const float* lw    = (const float*)d_in[3];
  const float* lb    = (const float*)d_in[4];
  const float* cw    = (const float*)d_in[5];
  const float* snz   = (const float*)d_in[6];
  const float* bias  = (const float*)d_in[7];
  float* out = (float*)d_out;

  char* ws = (char*)d_ws;
  bf16_t* xt   = (bf16_t*)ws;                   // 67,108,864 B
  bf16_t* bwf  = (bf16_t*)(ws + 67108864);      //  4,718,592 B
  float*  s    = (float*)(ws + 71827456);       //     32,768 B
  float*  sinv = (float*)(ws + 71860224);       //     32,768 B
  float*  wsq  = (float*)(ws + 71892992);       //  1,048,576 B
  char*   zbuf = ws + 72941568;                 //      4,096 B zeros

  k_style<<<dim3(2, 16), 256, 0, stream>>>(w, lw, lb, s);
  k_wprep<<<dim3(1024), 256, 0, stream>>>(cw, wsq, bwf, (f32x4*)zbuf);
  k_sigma<<<dim3(2, 16), 256, 0, stream>>>(s, wsq, sinv);
  k_xt<<<dim3(4, 64, 16), 256, 0, stream>>>(x, s, xt);
  k_conv<<<dim3(16, 4, 16), 256, 0, stream>>>(xt, bwf, sinv, noise, snz, bias, zbuf, out);
}

// Round 11
// 302.840 us; speedup vs baseline: 1.0386x; 1.0386x over previous
//
#include <hip/hip_runtime.h>
#include <hip/hip_bf16.h>
#include <stdint.h>

typedef __bf16 bf16_t;
typedef __bf16 bf16x8 __attribute__((ext_vector_type(8)));
typedef short short8 __attribute__((ext_vector_type(8)));
typedef float f32x4 __attribute__((ext_vector_type(4)));

#define RS512  0.044194173824159216f   // 1/sqrt(512)
#define RS4608 0.014731391274719739f   // 1/sqrt(512*9)

// ---------------- K1: style vector  s[b][c] = (w[b,:] . lw[c,:])/sqrt(512) + lb[c]
__global__ void k_style(const float* __restrict__ w, const float* __restrict__ lw,
                        const float* __restrict__ lb, float* __restrict__ s) {
  int b = blockIdx.y;
  int c = blockIdx.x * 256 + threadIdx.x;
  const float4* wr = (const float4*)(w + b * 512);
  const float4* lr = (const float4*)(lw + (size_t)c * 512);
  float acc = 0.f;
#pragma unroll 4
  for (int d = 0; d < 128; ++d) {
    float4 a = wr[d], q = lr[d];
    acc += a.x * q.x + a.y * q.y + a.z * q.z + a.w * q.w;
  }
  s[b * 512 + c] = acc * RS512 + lb[c];
}

// ---------------- K2: wsq + bf16 W fragments; also zero-fills the 4KB zero-region
__global__ void k_wprep(const float* __restrict__ cw, float* __restrict__ wsq,
                        bf16_t* __restrict__ bwf, f32x4* __restrict__ zb) {
  if (blockIdx.x == 0) zb[threadIdx.x] = (f32x4)0.f;  // 256*16B = 4KB zeros
  int idx = blockIdx.x * 256 + threadIdx.x;  // o*512 + i
  int o = idx >> 9, i = idx & 511;
  float v[9];
  float ss = 0.f;
#pragma unroll
  for (int t = 0; t < 9; ++t) {
    float x = cw[(size_t)idx * 9 + t] * RS4608;
    v[t] = x;
    ss += x * x;
  }
  wsq[idx] = ss;
  int lane = (o & 15) | (((i >> 3) & 3) << 4);
  int base_blk = (i >> 5) * 32 + (o >> 4);  // c32*32 + fo
#pragma unroll
  for (int t = 0; t < 9; ++t) {
    size_t e = ((size_t)(t * 512 + base_blk) << 9) + lane * 8 + (i & 7);
    bwf[e] = (bf16_t)v[t];
  }
}

// ---------------- K3: sigma_inv[b][o] = rsqrt( sum_i s[b,i]^2 * wsq[o,i] + eps )
__global__ void k_sigma(const float* __restrict__ s, const float* __restrict__ wsq,
                        float* __restrict__ sinv) {
  __shared__ float s2[512];
  int b = blockIdx.y;
  int o = blockIdx.x * 256 + threadIdx.x;
  for (int i = threadIdx.x; i < 512; i += 256) {
    float v = s[b * 512 + i];
    s2[i] = v * v;
  }
  __syncthreads();
  const float4* qr = (const float4*)(wsq + (size_t)o * 512);
  float acc = 0.f;
#pragma unroll 4
  for (int d = 0; d < 128; ++d) {
    float4 q = qr[d];
    acc += q.x * s2[4 * d] + q.y * s2[4 * d + 1] + q.z * s2[4 * d + 2] + q.w * s2[4 * d + 3];
  }
  sinv[b * 512 + o] = rsqrtf(acc + 1e-8f);
}

// ---------------- K4: xt[b][h][w][ch] = bf16( x[b][ch][h][w] * s[b][ch] ), slot-permuted
__global__ void k_xt(const float* __restrict__ x, const float* __restrict__ s,
                     bf16_t* __restrict__ xt) {
  int ic = blockIdx.x, h = blockIdx.y, b = blockIdx.z;
  __shared__ __align__(16) bf16_t tile[8192];
  int t = threadIdx.x;
  int wcol = t & 63;
  int g = t >> 6;
#pragma unroll
  for (int blk = 0; blk < 4; ++blk) {
    int grp = blk * 4 + g;
    bf16x8 vec;
#pragma unroll
    for (int k = 0; k < 8; ++k) {
      int i = ic * 128 + grp * 8 + k;
      float v = x[(((size_t)b * 512 + i) * 64 + h) * 64 + wcol] * s[b * 512 + i];
      vec[k] = (bf16_t)v;
    }
    int chunk = grp ^ (wcol & 15);
    *(bf16x8*)((char*)tile + wcol * 256 + chunk * 16) = vec;
  }
  __syncthreads();
#pragma unroll
  for (int j = 0; j < 4; ++j) {
    int flat = j * 256 + t;
    int wo = flat >> 4, ig8 = flat & 15;
    int chunk = ig8 ^ (wo & 15);
    bf16x8 v = *(bf16x8*)((char*)tile + wo * 256 + chunk * 16);
    int c32 = (ig8 >> 2);
    int slot = (ig8 & 3) ^ ((wo >> 1) & 3);
    *(bf16x8*)(xt + (((size_t)b * 64 + h) * 64 + wo) * 512 + ic * 128 + c32 * 32 + slot * 8) = v;
  }
}

// ---------------- K5: implicit-GEMM conv; 8-wave m64xn64, acc[4][4], 4 waves/SIMD
#define AS1 __attribute__((address_space(1)))
#define AS3 __attribute__((address_space(3)))

__device__ __forceinline__ void gl16(const void* g, void* l) {
  __builtin_amdgcn_global_load_lds((const AS1 void*)g, (AS3 void*)l, 16, 0, 0);
}

#define VMCNT(n) asm volatile("s_waitcnt vmcnt(" #n ")" ::: "memory")
#define BAR __builtin_amdgcn_s_barrier()

// LDS map: W[3 slabs][8192B] @0..24575 ; X[2 bufs][6 rows][4096B] @24576..73727
__global__ __launch_bounds__(512, 4) void k_conv(
    const bf16_t* __restrict__ xt, const bf16_t* __restrict__ bwf,
    const float* __restrict__ sinv, const float* __restrict__ noise,
    const float* __restrict__ snz, const float* __restrict__ bias,
    const char* __restrict__ zb, float* __restrict__ out) {
  __shared__ __align__(16) char lds[73728];

  const int t = threadIdx.x;
  const int rq = blockIdx.x;        // output rows h0..h0+3
  const int OY = blockIdx.y;        // o0 = OY*128
  const int b = blockIdx.z;
  const int h0 = rq * 4;
  const int lane = t & 63;
  const int wv = t >> 6;            // 8 waves
  const int wm = wv & 1;            // o-offset wm*64
  const int wn = wv >> 1;           // output row h0+wn

  // staging pointers (lane parts folded in once)
  const char* xg = (const char*)xt + (size_t)b * 4194304 + (lane >> 2) * 1024 + (lane & 3) * 16;
  const char* wgsrc = (const char*)bwf + ((OY * 8 + wv) << 10) + (lane << 4);

  f32x4 acc[4][4] = {};

  // per-wave X staging: 3 slots of the 24 (6 rows x 4 quarters); halo -> zero-region
  const char* xsrc[3];
  uint32_t xdst[3];
#pragma unroll
  for (int k = 0; k < 3; ++k) {
    int slot = wv * 3 + k, row = slot >> 2, q = slot & 3;
    int gr = h0 - 1 + row;
    bool valid = (unsigned)gr < 64u;
    xsrc[k] = valid ? (xg + (size_t)gr * 65536 + q * 16384) : (zb + lane * 16);
    xdst[k] = (uint32_t)(24576 + row * 4096 + q * 1024);
  }

  // LDS read offsets
  const uint32_t woff = (uint32_t)((wm << 12) + (lane << 4));  // fo = wm*4+mi within slab
  uint32_t pX[4][3];
#pragma unroll
  for (int j = 0; j < 4; ++j)
#pragma unroll
    for (int dk = 0; dk < 3; ++dk) {
      int icol = j * 16 + (lane & 15) + dk - 1;
      int ic2 = icol < 0 ? 0 : (icol > 63 ? 63 : icol);
      int slot = (lane >> 4) ^ ((ic2 >> 1) & 3);
      pX[j][dk] = (uint32_t)(24576 + wn * 4096 + ic2 * 64 + slot * 16);
    }
  const bool c0 = (lane & 15) == 0;
  const bool c15 = (lane & 15) == 15;

  auto stW = [&](uint32_t srcoff, int slab) {  // this wave's 1KB share of an 8KB slab
    gl16(wgsrc + srcoff, lds + slab * 8192 + (wv << 10));
  };
  auto stX = [&](int k, uint32_t cxoff, int xb) {  // this wave's 1KB X slot
    gl16(xsrc[k] + cxoff, lds + xdst[k] + (uint32_t)(xb * 24576));
  };

  // one tap: 4 A-reads + 4 B-reads + 16 MFMA
  auto COMP = [&](int JC, int XB) {
    const int ky = JC / 3, kx = JC % 3;
    bf16x8 af[4];
#pragma unroll
    for (int mi = 0; mi < 4; ++mi)
      af[mi] = *(const bf16x8*)(lds + (uint32_t)((JC % 3) * 8192) + woff + (uint32_t)(mi * 1024));
    bf16x8 bfr[4];
#pragma unroll
    for (int col = 0; col < 4; ++col) {
      short8 xv = *(const short8*)(lds + pX[col][kx] +
                                   (uint32_t)(XB * 24576 + ky * 4096));
      if (kx == 0 && col == 0) xv = c0 ? (short8)0 : xv;
      if (kx == 2 && col == 3) xv = c15 ? (short8)0 : xv;
      bfr[col] = __builtin_bit_cast(bf16x8, xv);
    }
    __builtin_amdgcn_s_setprio(1);
#pragma unroll
    for (int mi = 0; mi < 4; ++mi)
#pragma unroll
      for (int col = 0; col < 4; ++col)
        acc[mi][col] =
            __builtin_amdgcn_mfma_f32_16x16x32_bf16(af[mi], bfr[col], acc[mi][col], 0, 0, 0);
    __builtin_amdgcn_s_setprio(0);
  };

// phase: stage W[tap+2] (1 gl16), stage X slot (phases 0-2, 1 gl16), counted vmcnt, barrier,
// compute tap. Ledger (derived from per-wave issue order W-then-X):
//   steady {3,4,5,4,3,2,2,2,2} ; last chunk {2,2,2,2,2,2,2,1,0}
#define PHASE(CWB, CXB, JC, LAST, XB)                                          \
  {                                                                            \
    if ((JC) + 2 <= 8) stW((CWB) + (uint32_t)((JC) + 2) * 524288u, ((JC) + 2) % 3); \
    else if (!(LAST)) stW((CWB) + 32768u + (uint32_t)((JC) - 7) * 524288u, ((JC) + 2) % 3); \
    if (!(LAST) && (JC) < 3) stX((JC), (CXB), (XB) ^ 1);                       \
    if (LAST) {                                                                \
      if ((JC) <= 6) { VMCNT(2); }                                             \
      else if ((JC) == 7) { VMCNT(1); }                                        \
      else { VMCNT(0); }                                                       \
    } else {                                                                   \
      if ((JC) == 0 || (JC) == 4) { VMCNT(3); }                                \
      else if ((JC) == 1 || (JC) == 3) { VMCNT(4); }                           \
      else if ((JC) == 2) { VMCNT(5); }                                        \
      else { VMCNT(2); }                                                       \
    }                                                                          \
    __builtin_amdgcn_s_barrier();                                              \
    COMP((JC), (XB));                                                          \
  }

  // prologue: X[0] (halo slots read the zero-region) + W taps 0,1 -> slabs 0,1
#pragma unroll
  for (int k = 0; k < 3; ++k) stX(k, 0u, 0);
  stW(0u, 0);
  stW(524288u, 1);
  VMCNT(0); BAR;

  uint32_t cwb = 0, cxb = 64;
#pragma unroll 1
  for (int ci = 0; ci < 7; ++ci) {
#pragma unroll
    for (int jc = 0; jc < 9; ++jc) PHASE(cwb, cxb, jc, 0, 0);
    cwb += 32768u; cxb += 64u;
#pragma unroll
    for (int jc = 0; jc < 9; ++jc) PHASE(cwb, cxb, jc, 0, 1);
    cwb += 32768u; cxb += 64u;
  }
#pragma unroll
  for (int jc = 0; jc < 9; ++jc) PHASE(cwb, cxb, jc, 0, 0);  // chunk 14 (stages X[15])
  cwb += 32768u;
#pragma unroll
  for (int jc = 0; jc < 9; ++jc) PHASE(cwb, 0u, jc, 1, 1);   // chunk 15 (LAST)

  // epilogue: demod scale + noise + bias + leaky relu (one output row per wave)
  const float* sb = sinv + b * 512;
  const int og = OY * 128 + wm * 64 + ((lane >> 4) << 2);
  const int colb = lane & 15;
  const int prow = h0 + wn;
  float nzv[4];
#pragma unroll
  for (int col = 0; col < 4; ++col)
    nzv[col] = noise[(size_t)b * 4096 + prow * 64 + col * 16 + colb];
#pragma unroll
  for (int mi = 0; mi < 4; ++mi) {
#pragma unroll
    for (int r = 0; r < 4; ++r) {
      int o = og + mi * 16 + r;
      float sv = sb[o];
      float nw = snz[o];
      float bv = bias[o];
      float* orow = out + (((size_t)b * 512 + o) * 64 + prow) * 64;
#pragma unroll
      for (int col = 0; col < 4; ++col) {
        float v = acc[mi][col][r] * sv + nw * nzv[col] + bv;
        orow[col * 16 + colb] = v > 0.f ? v : 0.2f * v;
      }
    }
  }
}

extern "C" void kernel_launch(void* const* d_in, const int* in_sizes, int n_in,
                              void* d_out, int out_size, void* d_ws, size_t ws_size,
                              hipStream_t stream) {
  const float* x     = (const float*)d_in[0];
  const float* w     = (const float*)d_in[1];
  const float* noise = (const float*)d_in[2];
  const float* lw    = (const float*)d_in[3];
  const float* lb    = (const float*)d_in[4];
  const float* cw    = (const float*)d_in[5];
  const float* snz   = (const float*)d_in[6];
  const float* bias  = (const float*)d_in[7];
  float* out = (float*)d_out;

  char* ws = (char*)d_ws;
  bf16_t* xt   = (bf16_t*)ws;                   // 67,108,864 B
  bf16_t* bwf  = (bf16_t*)(ws + 67108864);      //  4,718,592 B
  float*  s    = (float*)(ws + 71827456);       //     32,768 B
  float*  sinv = (float*)(ws + 71860224);       //     32,768 B
  float*  wsq  = (float*)(ws + 71892992);       //  1,048,576 B
  char*   zbuf = ws + 72941568;                 //      4,096 B zeros

  k_style<<<dim3(2, 16), 256, 0, stream>>>(w, lw, lb, s);
  k_wprep<<<dim3(1024), 256, 0, stream>>>(cw, wsq, bwf, (f32x4*)zbuf);
  k_sigma<<<dim3(2, 16), 256, 0, stream>>>(s, wsq, sinv);
  k_xt<<<dim3(4, 64, 16), 256, 0, stream>>>(x, s, xt);
  k_conv<<<dim3(16, 4, 16), 512, 0, stream>>>(xt, bwf, sinv, noise, snz, bias, zbuf, out);
}